// Round 5
// baseline (2809.422 us; speedup 1.0000x reference)
//
#include <hip/hip_runtime.h>
#include <hip/hip_bf16.h>
#include <math.h>

#define NT  512
#define NWG 128

typedef __attribute__((ext_vector_type(8))) short bf16x8;
typedef __attribute__((ext_vector_type(4))) float f32x4;

__device__ __forceinline__ unsigned short f2bf(float f) {
    union { __hip_bfloat16 h; unsigned short s; } u;
    u.h = __float2bfloat16(f);
    return u.s;
}
__device__ __forceinline__ float bf2f(unsigned short s) {
    union { float f; unsigned u; } v; v.u = ((unsigned)s) << 16; return v.f;
}
// state LDS swizzle (R2-R4 verified): conflict-free MFMA A-frag reads
__device__ __forceinline__ int st_off(int row, int k) {
    return row * 512 + ((k & 504) ^ ((row & 7) << 3)) + (k & 7);
}
// lgkmcnt-only barrier: LDS ordering without draining in-flight global loads
__device__ __forceinline__ void barL() {
    asm volatile("s_waitcnt lgkmcnt(0)" ::: "memory");
    __builtin_amdgcn_s_barrier();
}

// fp32 [k][u] (512x512) -> MFMA B-fragments, tile = kb*32+ub:
// lane l holds B[kb*32+(l>>4)*8+j][ub*16+(l&15)], j=0..7 (4 u32 bf16-pairs).
__global__ void conv_frag(const float* __restrict__ Wa, const float* __restrict__ Wb,
                          unsigned int* __restrict__ outa, unsigned int* __restrict__ outb) {
    const int bid = blockIdx.x;
    const float* W    = (bid < 512) ? Wa : Wb;
    unsigned int* out = (bid < 512) ? outa : outb;
    const int tile = bid & 511;
    const int l    = threadIdx.x;
    const int kb = tile >> 5, ub = tile & 31;
    const int k0 = kb * 32 + (l >> 4) * 8;
    const int u  = ub * 16 + (l & 15);
    unsigned v[4];
    #pragma unroll
    for (int p = 0; p < 4; ++p) {
        unsigned lo = f2bf(W[(size_t)(k0 + 2 * p) * 512 + u]);
        unsigned hi = f2bf(W[(size_t)(k0 + 2 * p + 1) * 512 + u]);
        v[p] = lo | (hi << 16);
    }
    *(uint4*)(out + (size_t)(tile * 64 + l) * 4) = make_uint4(v[0], v[1], v[2], v[3]);
}

#define MFMA(A, B, C) __builtin_amdgcn_mfma_f32_16x16x32_bf16((A), (B), (C), 0, 0, 0)

__global__ __launch_bounds__(NT)
__attribute__((amdgpu_waves_per_eu(2, 2)))       // hard 256-VGPR budget: no spills
void rnn2d_v5(
    const int*   __restrict__ x,
    const float* __restrict__ Wih,
    const float* __restrict__ Wiv,
    const float* __restrict__ bch,
    const float* __restrict__ Wout,
    const float* __restrict__ bout,
    const unsigned int* __restrict__ wchf,
    const unsigned int* __restrict__ wcvf,
    float*       __restrict__ out)
{
    __shared__ __attribute__((aligned(16))) bf16x8        wlds[8 * 10 * 64];   // 80 KB Wch tier-2
    __shared__ __attribute__((aligned(16))) unsigned short stm[32 * 512];      // 32 KB states
    __shared__ __attribute__((aligned(16))) unsigned short Vb[32 * 512];       // 32 KB V (bf16)
    __shared__ __attribute__((aligned(16))) unsigned short hb[2][2][512];      // 4 KB h dbuf
    __shared__ __attribute__((aligned(16))) float          part[512 * 2];      // 4 KB pre-acts
    __shared__ int    xc[2][2][16];                                            // 256 B spins
    __shared__ float4 wred[2][8];                                              // 256 B

    const int tid = threadIdx.x;
    const int b0  = blockIdx.x * 2;
    const int w   = tid >> 6, l = tid & 63;
    const int r   = l & 15,  hi4 = l >> 4, rb = r & 1;

    // per-u (u == tid) weight scalars
    const float wih0 = Wih[tid], wih1 = Wih[512 + tid];
    const float wiv0 = Wiv[tid], wiv1 = Wiv[512 + tid];
    const float bc   = bch[tid];
    const float wo0  = Wout[2 * tid], wo1 = Wout[2 * tid + 1];
    const float bo0  = bout[0],       bo1 = bout[1];

    const bf16x8* __restrict__ WF = (const bf16x8*)wchf;
    const bf16x8* __restrict__ VF = (const bf16x8*)wcvf;

    for (int idx = tid; idx < 32 * 512 / 2; idx += NT) {
        ((unsigned*)stm)[idx] = 0;
        ((unsigned*)Vb)[idx]  = 0;
    }

    // tier-1: register-resident Wch (n-tiles w*4+0, w*4+1)
    bf16x8 wreg[32];
    #pragma unroll
    for (int kb = 0; kb < 16; ++kb) {
        wreg[2 * kb]     = WF[(kb * 32 + w * 4 + 0) * 64 + l];
        wreg[2 * kb + 1] = WF[(kb * 32 + w * 4 + 1) * 64 + l];
    }
    // tier-2: LDS-resident (n-tile w*4+2, kb 0..9)
    #pragma unroll
    for (int f = 0; f < 10; ++f)
        wlds[(w * 10 + f) * 64 + l] = WF[(f * 32 + w * 4 + 2) * 64 + l];
    // tier-3 stream buffer, preloaded with group-A (t2 kb10-15, t3 kb0-4)
    bf16x8 S[11];
    #pragma unroll
    for (int j = 0; j < 11; ++j)
        S[j] = WF[((j < 6) ? ((10 + j) * 32 + w * 4 + 2) : ((j - 6) * 32 + w * 4 + 3)) * 64 + l];

    float logp0 = 0.f, logp1 = 0.f;
    int p = 0;

    for (int i = 0; i < 16; ++i) {
        const int dir = (i & 1) ? -1 : 1;

        // ---- per-row V-pass: Vb = st(prev row) @ Wcv, in two n-halves
        //      (vacc only 16 VGPRs live at a time; each Wcv frag read once)
        if (i > 0) {
            const int kl = hi4 * 8;
            #pragma unroll
            for (int half = 0; half < 2; ++half) {
                f32x4 vacc[2][2];
                #pragma unroll
                for (int m = 0; m < 2; ++m)
                    #pragma unroll
                    for (int t4 = 0; t4 < 2; ++t4) vacc[m][t4] = (f32x4)(0.f);
                for (int kb = 0; kb < 16; ++kb) {
                    const int ka = kb * 32 + kl;
                    bf16x8 A0 = *(const bf16x8*)&stm[st_off(r,      ka)];
                    bf16x8 A1 = *(const bf16x8*)&stm[st_off(r + 16, ka)];
                    #pragma unroll
                    for (int t4 = 0; t4 < 2; ++t4) {
                        bf16x8 Bf = VF[(size_t)(kb * 32 + w * 4 + half * 2 + t4) * 64 + l];
                        vacc[0][t4] = MFMA(A0, Bf, vacc[0][t4]);
                        vacc[1][t4] = MFMA(A1, Bf, vacc[1][t4]);
                    }
                }
                #pragma unroll
                for (int m = 0; m < 2; ++m)
                    #pragma unroll
                    for (int t4 = 0; t4 < 2; ++t4)
                        #pragma unroll
                        for (int q = 0; q < 4; ++q)
                            Vb[(m * 16 + hi4 * 4 + q) * 512 +
                               (w * 4 + half * 2 + t4) * 16 + r] = f2bf(vacc[m][t4][q]);
            }
            // re-arm S with group-A (skipped at t==15 so V-pass ran with S dead)
            #pragma unroll
            for (int j = 0; j < 11; ++j)
                S[j] = WF[((j < 6) ? ((10 + j) * 32 + w * 4 + 2)
                                   : ((j - 6) * 32 + w * 4 + 3)) * 64 + l];
        }

        // x-row cache: [b][0]=row i, [b][1]=row i-1
        if (tid < 64) {
            const int b = tid >> 5, rs = (tid >> 4) & 1, c = tid & 15;
            int v = 0;
            if (rs == 0)      v = x[(b0 + b) * 256 + i * 16 + c];
            else if (i > 0)   v = x[(b0 + b) * 256 + (i - 1) * 16 + c];
            xc[b][rs][c] = v;
        }
        ((unsigned*)hb)[tid] = 0;    // zero hb[0] (p==0 at row start)
        __syncthreads();

        for (int t = 0; t < 16; ++t) {
            const int c = (dir == 1) ? t : 15 - t;

            f32x4 acc0 = (f32x4)(0.f), acc1 = (f32x4)(0.f),
                  acc2 = (f32x4)(0.f), acc3 = (f32x4)(0.f);

            #define AF(KB) (*(const bf16x8*)&hb[p][rb][(((KB) * 4 + hi4) ^ rb) << 3])

            // L1: kb 0-4 — tier1 + S group-A tail (acc3 kb0-4 = S[6..10])
            #pragma unroll
            for (int kb = 0; kb < 5; ++kb) {
                bf16x8 Af = AF(kb);
                acc0 = MFMA(Af, wreg[2 * kb],     acc0);
                acc1 = MFMA(Af, wreg[2 * kb + 1], acc1);
                acc3 = MFMA(Af, S[6 + kb],        acc3);
            }
            // L2: kb 10-15 — tier1 + S group-A head (acc2 kb10-15 = S[0..5])
            #pragma unroll
            for (int kb = 10; kb < 16; ++kb) {
                bf16x8 Af = AF(kb);
                acc0 = MFMA(Af, wreg[2 * kb],     acc0);
                acc1 = MFMA(Af, wreg[2 * kb + 1], acc1);
                acc2 = MFMA(Af, S[kb - 10],       acc2);
            }
            // issue S <- group-B (this step: acc3 kb5-15)
            #pragma unroll
            for (int j = 0; j < 11; ++j)
                S[j] = WF[((5 + j) * 32 + w * 4 + 3) * 64 + l];
            // L3: kb 0-9 — tier2 LDS (acc2), tier1 remainder kb5-9
            #pragma unroll
            for (int kb = 0; kb < 10; ++kb) {
                bf16x8 Af = AF(kb);
                bf16x8 Bw = wlds[(w * 10 + kb) * 64 + l];
                acc2 = MFMA(Af, Bw, acc2);
                if (kb >= 5) {
                    acc0 = MFMA(Af, wreg[2 * kb],     acc0);
                    acc1 = MFMA(Af, wreg[2 * kb + 1], acc1);
                }
            }
            // L4: kb 5-15 — S group-B (acc3)
            #pragma unroll
            for (int kb = 5; kb < 16; ++kb) {
                bf16x8 Af = AF(kb);
                acc3 = MFMA(Af, S[kb - 5], acc3);
            }
            // issue S <- group-A for next step (skip at t==15; re-armed after V-pass)
            if (t < 15) {
                #pragma unroll
                for (int j = 0; j < 11; ++j)
                    S[j] = WF[((j < 6) ? ((10 + j) * 32 + w * 4 + 2)
                                       : ((j - 6) * 32 + w * 4 + 3)) * 64 + l];
            }
            #undef AF

            // C rows 0,1 (= batches) live in lanes 0-15, regs 0,1
            if (l < 16) {
                *(float2*)&part[(w * 64 +  0 + l) * 2] = make_float2(acc0[0], acc0[1]);
                *(float2*)&part[(w * 64 + 16 + l) * 2] = make_float2(acc1[0], acc1[1]);
                *(float2*)&part[(w * 64 + 32 + l) * 2] = make_float2(acc2[0], acc2[1]);
                *(float2*)&part[(w * 64 + 48 + l) * 2] = make_float2(acc3[0], acc3[1]);
            }
            barL();   // [B]

            // ---- epilogue: u = tid, both batches ----
            const int  cl   = c - dir;
            const bool hasL = (t > 0);
            const bool hasV = (i > 0);
            const float2 pa = *(const float2*)&part[tid * 2];
            float v0 = pa.x + bf2f(Vb[(c * 2 + 0) * 512 + tid]) + bc;
            float v1 = pa.y + bf2f(Vb[(c * 2 + 1) * 512 + tid]) + bc;
            if (hasL) { v0 += xc[0][0][cl] ? wih1 : wih0;  v1 += xc[1][0][cl] ? wih1 : wih0; }
            if (hasV) { v0 += xc[0][1][c]  ? wiv1 : wiv0;  v1 += xc[1][1][c]  ? wiv1 : wiv0; }
            v0 = v0 > 0.f ? v0 : expm1f(v0);
            v1 = v1 > 0.f ? v1 : expm1f(v1);
            hb[p ^ 1][0][(((tid >> 3) ^ 0) << 3) | (tid & 7)] = f2bf(v0);
            hb[p ^ 1][1][(((tid >> 3) ^ 1) << 3) | (tid & 7)] = f2bf(v1);
            stm[st_off(c * 2 + 0, tid)] = f2bf(v0);
            stm[st_off(c * 2 + 1, tid)] = f2bf(v1);
            const int sc0 = xc[0][0][c], sc1 = xc[1][0][c];   // read pre-barrier
            float lp0 = v0 * wo0, lp1 = v0 * wo1, lp2 = v1 * wo0, lp3 = v1 * wo1;
            #pragma unroll
            for (int off = 32; off; off >>= 1) {
                lp0 += __shfl_down(lp0, off);
                lp1 += __shfl_down(lp1, off);
                lp2 += __shfl_down(lp2, off);
                lp3 += __shfl_down(lp3, off);
            }
            if (l == 0) wred[t & 1][w] = make_float4(lp0, lp1, lp2, lp3);
            barL();   // [C]

            // ---- logits: all threads redundantly (no straggler wave) ----
            float g00 = bo0, g01 = bo1, g10 = bo0, g11 = bo1;
            #pragma unroll
            for (int ww = 0; ww < 8; ++ww) {
                const float4 v4 = wred[t & 1][ww];
                g00 += v4.x;  g01 += v4.y;  g10 += v4.z;  g11 += v4.w;
            }
            {
                const float m0 = fmaxf(g00, g01), m1 = fmaxf(g10, g11);
                const float ls0 = m0 + log1pf(expf(fminf(g00, g01) - m0));
                const float ls1 = m1 + log1pf(expf(fminf(g10, g11) - m1));
                logp0 += (sc0 ? g01 : g00) - ls0;
                logp1 += (sc1 ? g11 : g10) - ls1;
            }
            p ^= 1;
        }
    }

    if (tid < 2) {
        float v = tid ? logp1 : logp0;
        if (isnan(v)) v = 0.f;
        else if (isinf(v)) v = v > 0.f ? 3.4028235e38f : -3.4028235e38f;
        out[b0 + tid] = v;
    }
}

extern "C" void kernel_launch(void* const* d_in, const int* in_sizes, int n_in,
                              void* d_out, int out_size, void* d_ws, size_t ws_size,
                              hipStream_t stream) {
    const int*   x    = (const int*)  d_in[0];
    const float* Wih  = (const float*)d_in[1];
    const float* Wiv  = (const float*)d_in[2];
    const float* Wch  = (const float*)d_in[3];
    const float* bch  = (const float*)d_in[4];
    const float* Wcv  = (const float*)d_in[5];
    const float* Wout = (const float*)d_in[6];
    const float* bout = (const float*)d_in[7];

    unsigned int* ws_wch = (unsigned int*)d_ws;                          // 512 KB
    unsigned int* ws_wcv = (unsigned int*)((char*)d_ws + 512 * 1024);    // 512 KB

    conv_frag<<<1024, 64, 0, stream>>>(Wch, Wcv, ws_wch, ws_wcv);
    rnn2d_v5<<<NWG, NT, 0, stream>>>(x, Wih, Wiv, bch, Wout, bout,
                                     ws_wch, ws_wcv, (float*)d_out);
}

// Round 6
// 2513.305 us; speedup vs baseline: 1.1178x; 1.1178x over previous
//
#include <hip/hip_runtime.h>
#include <hip/hip_bf16.h>
#include <math.h>

#define NT  512
#define NWG 128

typedef __attribute__((ext_vector_type(8))) short bf16x8;
typedef __attribute__((ext_vector_type(4))) float f32x4;

__device__ __forceinline__ unsigned short f2bf(float f) {
    union { __hip_bfloat16 h; unsigned short s; } u;
    u.h = __float2bfloat16(f);
    return u.s;
}
__device__ __forceinline__ float bf2f(unsigned short s) {
    union { float f; unsigned u; } v; v.u = ((unsigned)s) << 16; return v.f;
}
// state LDS swizzle (R2-R5 verified): conflict-free MFMA A-frag reads
__device__ __forceinline__ int st_off(int row, int k) {
    return row * 512 + ((k & 504) ^ ((row & 7) << 3)) + (k & 7);
}
// lgkmcnt-only barrier: LDS ordering without draining in-flight global loads
__device__ __forceinline__ void barL() {
    asm volatile("s_waitcnt lgkmcnt(0)" ::: "memory");
    __builtin_amdgcn_s_barrier();
}

// MFMA with accumulator pinned in AGPRs; B from AGPR (weights live there) or VGPR
__device__ __forceinline__ void mfma_a(f32x4& d, bf16x8 a, bf16x8 b) {
    asm("v_mfma_f32_16x16x32_bf16 %0, %1, %2, %0" : "+a"(d) : "v"(a), "a"(b));
}
__device__ __forceinline__ void mfma_v(f32x4& d, bf16x8 a, bf16x8 b) {
    asm("v_mfma_f32_16x16x32_bf16 %0, %1, %2, %0" : "+a"(d) : "v"(a), "v"(b));
}

// fp32 [k][u] (512x512) -> MFMA B-fragments, tile = kb*32+ub:
// lane l holds B[kb*32+(l>>4)*8+j][ub*16+(l&15)], j=0..7 (4 u32 bf16-pairs).
__global__ void conv_frag(const float* __restrict__ Wa, const float* __restrict__ Wb,
                          unsigned int* __restrict__ outa, unsigned int* __restrict__ outb) {
    const int bid = blockIdx.x;
    const float* W    = (bid < 512) ? Wa : Wb;
    unsigned int* out = (bid < 512) ? outa : outb;
    const int tile = bid & 511;
    const int l    = threadIdx.x;
    const int kb = tile >> 5, ub = tile & 31;
    const int k0 = kb * 32 + (l >> 4) * 8;
    const int u  = ub * 16 + (l & 15);
    unsigned v[4];
    #pragma unroll
    for (int p = 0; p < 4; ++p) {
        unsigned lo = f2bf(W[(size_t)(k0 + 2 * p) * 512 + u]);
        unsigned hi = f2bf(W[(size_t)(k0 + 2 * p + 1) * 512 + u]);
        v[p] = lo | (hi << 16);
    }
    *(uint4*)(out + (size_t)(tile * 64 + l) * 4) = make_uint4(v[0], v[1], v[2], v[3]);
}

#define IMFMA(A, B, C) __builtin_amdgcn_mfma_f32_16x16x32_bf16((A), (B), (C), 0, 0, 0)

__global__ __launch_bounds__(NT)
__attribute__((amdgpu_waves_per_eu(2, 2)))
void rnn2d_v6(
    const int*   __restrict__ x,
    const float* __restrict__ Wih,
    const float* __restrict__ Wiv,
    const float* __restrict__ bch,
    const float* __restrict__ Wout,
    const float* __restrict__ bout,
    const unsigned int* __restrict__ wchf,
    const unsigned int* __restrict__ wcvf,
    float*       __restrict__ out)
{
    __shared__ __attribute__((aligned(16))) bf16x8        wlds[8 * 10 * 64];   // 80 KB Wch LDS tier
    __shared__ __attribute__((aligned(16))) unsigned short stm[32 * 512];      // 32 KB states
    __shared__ __attribute__((aligned(16))) unsigned short Vb[32 * 512];       // 32 KB V (bf16)
    __shared__ __attribute__((aligned(16))) unsigned short hb[2][2][512];      // 4 KB h dbuf
    __shared__ __attribute__((aligned(16))) float          part[512 * 2];      // 4 KB pre-acts
    __shared__ int    xc[2][2][16];
    __shared__ float4 wred[2][8];

    const int tid = threadIdx.x;
    const int b0  = blockIdx.x * 2;
    const int w   = tid >> 6, l = tid & 63;
    const int r   = l & 15,  hi4 = l >> 4, rb = r & 1;

    const float wih0 = Wih[tid], wih1 = Wih[512 + tid];
    const float wiv0 = Wiv[tid], wiv1 = Wiv[512 + tid];
    const float bc   = bch[tid];
    const float wo0  = Wout[2 * tid], wo1 = Wout[2 * tid + 1];
    const float bo0  = bout[0],       bo1 = bout[1];

    const bf16x8* __restrict__ WF = (const bf16x8*)wchf;
    const bf16x8* __restrict__ VF = (const bf16x8*)wcvf;

    for (int idx = tid; idx < 32 * 512 / 2; idx += NT) {
        ((unsigned*)stm)[idx] = 0;
        ((unsigned*)Vb)[idx]  = 0;
    }

    // ---- Wch tiers (per wave: n-tiles nt0..nt3 = w*4+0..3, kb 0..15) ----
    // arch-VGPR tier: nt0 kb0-11 (48 regs)
    bf16x8 wregV[12];
    #pragma unroll
    for (int kb = 0; kb < 12; ++kb)
        wregV[kb] = WF[(kb * 32 + w * 4 + 0) * 64 + l];
    // AGPR tier: nt1 kb0-15 (64 regs) + nt2 kb0-7 (32 regs)
    bf16x8 wagA[16];
    #pragma unroll
    for (int kb = 0; kb < 16; ++kb)
        wagA[kb] = WF[(kb * 32 + w * 4 + 1) * 64 + l];
    bf16x8 wagB[8];
    #pragma unroll
    for (int kb = 0; kb < 8; ++kb)
        wagB[kb] = WF[(kb * 32 + w * 4 + 2) * 64 + l];
    // LDS tier: nt0 kb12-15 (q0-3), nt2 kb8-13 (q4-9)
    #pragma unroll
    for (int q = 0; q < 4; ++q)
        wlds[(w * 10 + q) * 64 + l] = WF[((12 + q) * 32 + w * 4 + 0) * 64 + l];
    #pragma unroll
    for (int q = 0; q < 6; ++q)
        wlds[(w * 10 + 4 + q) * 64 + l] = WF[((8 + q) * 32 + w * 4 + 2) * 64 + l];
    // stream buffer, preloaded with G_early = nt3 kb0-8
    bf16x8 S[9];
    #pragma unroll
    for (int j = 0; j < 9; ++j)
        S[j] = WF[(j * 32 + w * 4 + 3) * 64 + l];

    float logp0 = 0.f, logp1 = 0.f;
    int p = 0;

    for (int i = 0; i < 16; ++i) {
        const int dir = (i & 1) ? -1 : 1;

        // ---- per-row V-pass: Vb = st(prev row) @ Wcv, two n-halves ----
        if (i > 0) {
            const int kl = hi4 * 8;
            #pragma unroll
            for (int half = 0; half < 2; ++half) {
                f32x4 vacc[2][2];
                #pragma unroll
                for (int m = 0; m < 2; ++m)
                    #pragma unroll
                    for (int t4 = 0; t4 < 2; ++t4) vacc[m][t4] = (f32x4)(0.f);
                for (int kb = 0; kb < 16; ++kb) {
                    const int ka = kb * 32 + kl;
                    bf16x8 A0 = *(const bf16x8*)&stm[st_off(r,      ka)];
                    bf16x8 A1 = *(const bf16x8*)&stm[st_off(r + 16, ka)];
                    #pragma unroll
                    for (int t4 = 0; t4 < 2; ++t4) {
                        bf16x8 Bf = VF[(size_t)(kb * 32 + w * 4 + half * 2 + t4) * 64 + l];
                        vacc[0][t4] = IMFMA(A0, Bf, vacc[0][t4]);
                        vacc[1][t4] = IMFMA(A1, Bf, vacc[1][t4]);
                    }
                }
                #pragma unroll
                for (int m = 0; m < 2; ++m)
                    #pragma unroll
                    for (int t4 = 0; t4 < 2; ++t4)
                        #pragma unroll
                        for (int q = 0; q < 4; ++q)
                            Vb[(m * 16 + hi4 * 4 + q) * 512 +
                               (w * 4 + half * 2 + t4) * 16 + r] = f2bf(vacc[m][t4][q]);
            }
            // re-arm S with G_early (stream issue was skipped at t==15)
            #pragma unroll
            for (int j = 0; j < 9; ++j)
                S[j] = WF[(j * 32 + w * 4 + 3) * 64 + l];
        }

        // x-row cache: [b][0]=row i, [b][1]=row i-1
        if (tid < 64) {
            const int b = tid >> 5, rs = (tid >> 4) & 1, c = tid & 15;
            int v = 0;
            if (rs == 0)      v = x[(b0 + b) * 256 + i * 16 + c];
            else if (i > 0)   v = x[(b0 + b) * 256 + (i - 1) * 16 + c];
            xc[b][rs][c] = v;
        }
        ((unsigned*)hb)[tid] = 0;    // zero hb[0] (p==0 at row start)
        __syncthreads();

        for (int t = 0; t < 16; ++t) {
            const int c = (dir == 1) ? t : 15 - t;

            f32x4 acc0 = (f32x4)(0.f), acc1 = (f32x4)(0.f),
                  acc2 = (f32x4)(0.f), acc3 = (f32x4)(0.f);

            #define AF(KB) (*(const bf16x8*)&hb[p][rb][(((KB) * 4 + hi4) ^ rb) << 3])

            // sweep A: kb 0-8 (S = G_early = nt3 kb0-8); one A-frag read, 4 uses
            #pragma unroll
            for (int kb = 0; kb < 9; ++kb) {
                bf16x8 af = AF(kb);
                mfma_v(acc3, af, S[kb]);
                mfma_a(acc1, af, wagA[kb]);
                if (kb < 8) mfma_a(acc2, af, wagB[kb]);
                else        mfma_v(acc2, af, wlds[(w * 10 + 4) * 64 + l]);
                mfma_v(acc0, af, wregV[kb]);
            }
            // issue S <- G_late (nt3 kb9-15, nt2 kb14-15)
            #pragma unroll
            for (int j = 0; j < 7; ++j)
                S[j] = WF[((9 + j) * 32 + w * 4 + 3) * 64 + l];
            S[7] = WF[(14 * 32 + w * 4 + 2) * 64 + l];
            S[8] = WF[(15 * 32 + w * 4 + 2) * 64 + l];
            // sweep B: kb 9-15
            #pragma unroll
            for (int kb = 9; kb < 16; ++kb) {
                bf16x8 af = AF(kb);
                mfma_a(acc1, af, wagA[kb]);
                if (kb <= 11) mfma_v(acc0, af, wregV[kb]);
                else          mfma_v(acc0, af, wlds[(w * 10 + (kb - 12)) * 64 + l]);
                if (kb <= 13) mfma_v(acc2, af, wlds[(w * 10 + 4 + (kb - 8)) * 64 + l]);
                else          mfma_v(acc2, af, S[7 + (kb - 14)]);
                mfma_v(acc3, af, S[kb - 9]);
            }
            // issue S <- G_early for next step (skip at t==15; re-armed after V-pass)
            if (t < 15) {
                #pragma unroll
                for (int j = 0; j < 9; ++j)
                    S[j] = WF[(j * 32 + w * 4 + 3) * 64 + l];
            }
            #undef AF

            // C rows 0,1 (= batches) live in lanes 0-15, regs 0,1
            if (l < 16) {
                *(float2*)&part[(w * 64 +  0 + l) * 2] = make_float2(acc0[0], acc0[1]);
                *(float2*)&part[(w * 64 + 16 + l) * 2] = make_float2(acc1[0], acc1[1]);
                *(float2*)&part[(w * 64 + 32 + l) * 2] = make_float2(acc2[0], acc2[1]);
                *(float2*)&part[(w * 64 + 48 + l) * 2] = make_float2(acc3[0], acc3[1]);
            }
            barL();   // [B]

            // ---- epilogue: u = tid, both batches ----
            const int  cl   = c - dir;
            const bool hasL = (t > 0);
            const bool hasV = (i > 0);
            const float2 pa = *(const float2*)&part[tid * 2];
            float v0 = pa.x + bf2f(Vb[(c * 2 + 0) * 512 + tid]) + bc;
            float v1 = pa.y + bf2f(Vb[(c * 2 + 1) * 512 + tid]) + bc;
            if (hasL) { v0 += xc[0][0][cl] ? wih1 : wih0;  v1 += xc[1][0][cl] ? wih1 : wih0; }
            if (hasV) { v0 += xc[0][1][c]  ? wiv1 : wiv0;  v1 += xc[1][1][c]  ? wiv1 : wiv0; }
            v0 = v0 > 0.f ? v0 : expm1f(v0);
            v1 = v1 > 0.f ? v1 : expm1f(v1);
            hb[p ^ 1][0][(((tid >> 3) ^ 0) << 3) | (tid & 7)] = f2bf(v0);
            hb[p ^ 1][1][(((tid >> 3) ^ 1) << 3) | (tid & 7)] = f2bf(v1);
            stm[st_off(c * 2 + 0, tid)] = f2bf(v0);
            stm[st_off(c * 2 + 1, tid)] = f2bf(v1);
            const int sc0 = xc[0][0][c], sc1 = xc[1][0][c];
            float lp0 = v0 * wo0, lp1 = v0 * wo1, lp2 = v1 * wo0, lp3 = v1 * wo1;
            #pragma unroll
            for (int off = 32; off; off >>= 1) {
                lp0 += __shfl_down(lp0, off);
                lp1 += __shfl_down(lp1, off);
                lp2 += __shfl_down(lp2, off);
                lp3 += __shfl_down(lp3, off);
            }
            if (l == 0) wred[t & 1][w] = make_float4(lp0, lp1, lp2, lp3);
            barL();   // [C]

            // ---- logits: all threads redundantly (no straggler wave) ----
            float g00 = bo0, g01 = bo1, g10 = bo0, g11 = bo1;
            #pragma unroll
            for (int ww = 0; ww < 8; ++ww) {
                const float4 v4 = wred[t & 1][ww];
                g00 += v4.x;  g01 += v4.y;  g10 += v4.z;  g11 += v4.w;
            }
            {
                const float m0 = fmaxf(g00, g01), m1 = fmaxf(g10, g11);
                const float ls0 = m0 + log1pf(expf(fminf(g00, g01) - m0));
                const float ls1 = m1 + log1pf(expf(fminf(g10, g11) - m1));
                logp0 += (sc0 ? g01 : g00) - ls0;
                logp1 += (sc1 ? g11 : g10) - ls1;
            }
            p ^= 1;
        }
    }

    if (tid < 2) {
        float v = tid ? logp1 : logp0;
        if (isnan(v)) v = 0.f;
        else if (isinf(v)) v = v > 0.f ? 3.4028235e38f : -3.4028235e38f;
        out[b0 + tid] = v;
    }
}

extern "C" void kernel_launch(void* const* d_in, const int* in_sizes, int n_in,
                              void* d_out, int out_size, void* d_ws, size_t ws_size,
                              hipStream_t stream) {
    const int*   x    = (const int*)  d_in[0];
    const float* Wih  = (const float*)d_in[1];
    const float* Wiv  = (const float*)d_in[2];
    const float* Wch  = (const float*)d_in[3];
    const float* bch  = (const float*)d_in[4];
    const float* Wcv  = (const float*)d_in[5];
    const float* Wout = (const float*)d_in[6];
    const float* bout = (const float*)d_in[7];

    unsigned int* ws_wch = (unsigned int*)d_ws;                          // 512 KB
    unsigned int* ws_wcv = (unsigned int*)((char*)d_ws + 512 * 1024);    // 512 KB

    conv_frag<<<1024, 64, 0, stream>>>(Wch, Wcv, ws_wch, ws_wcv);
    rnn2d_v6<<<NWG, NT, 0, stream>>>(x, Wih, Wiv, bch, Wout, bout,
                                     ws_wch, ws_wcv, (float*)d_out);
}

// Round 7
// 2180.941 us; speedup vs baseline: 1.2882x; 1.1524x over previous
//
#include <hip/hip_runtime.h>
#include <hip/hip_bf16.h>
#include <math.h>

#define NT  512
#define NWG 128

typedef __attribute__((ext_vector_type(8))) short bf16x8;
typedef __attribute__((ext_vector_type(4))) float f32x4;

__device__ __forceinline__ unsigned short f2bf(float f) {
    union { __hip_bfloat16 h; unsigned short s; } u;
    u.h = __float2bfloat16(f);
    return u.s;
}
__device__ __forceinline__ float bf2f(unsigned short s) {
    union { float f; unsigned u; } v; v.u = ((unsigned)s) << 16; return v.f;
}
// state LDS swizzle (R2-R6 verified): conflict-free MFMA A-frag reads
__device__ __forceinline__ int st_off(int row, int k) {
    return row * 512 + ((k & 504) ^ ((row & 7) << 3)) + (k & 7);
}
// lgkmcnt-only barrier: LDS ordering without draining in-flight global loads
__device__ __forceinline__ void barL() {
    asm volatile("s_waitcnt lgkmcnt(0)" ::: "memory");
    __builtin_amdgcn_s_barrier();
}

// MFMA, accumulator pinned in AGPRs; B from AGPR (resident weights) or VGPR
__device__ __forceinline__ void mfma_a(f32x4& d, bf16x8 a, bf16x8 b) {
    asm("v_mfma_f32_16x16x32_bf16 %0, %1, %2, %0" : "+a"(d) : "v"(a), "a"(b));
}
__device__ __forceinline__ void mfma_v(f32x4& d, bf16x8 a, bf16x8 b) {
    asm("v_mfma_f32_16x16x32_bf16 %0, %1, %2, %0" : "+a"(d) : "v"(a), "v"(b));
}

// fp32 [k][u] (512x512) -> MFMA B-fragments, tile = kb*32+ub:
// lane l holds B[kb*32+(l>>4)*8+j][ub*16+(l&15)], j=0..7 (4 u32 bf16-pairs).
__global__ void conv_frag(const float* __restrict__ Wa, const float* __restrict__ Wb,
                          unsigned int* __restrict__ outa, unsigned int* __restrict__ outb) {
    const int bid = blockIdx.x;
    const float* W    = (bid < 512) ? Wa : Wb;
    unsigned int* out = (bid < 512) ? outa : outb;
    const int tile = bid & 511;
    const int l    = threadIdx.x;
    const int kb = tile >> 5, ub = tile & 31;
    const int k0 = kb * 32 + (l >> 4) * 8;
    const int u  = ub * 16 + (l & 15);
    unsigned v[4];
    #pragma unroll
    for (int p = 0; p < 4; ++p) {
        unsigned lo = f2bf(W[(size_t)(k0 + 2 * p) * 512 + u]);
        unsigned hi = f2bf(W[(size_t)(k0 + 2 * p + 1) * 512 + u]);
        v[p] = lo | (hi << 16);
    }
    *(uint4*)(out + (size_t)(tile * 64 + l) * 4) = make_uint4(v[0], v[1], v[2], v[3]);
}

#define IMFMA(A, B, C) __builtin_amdgcn_mfma_f32_16x16x32_bf16((A), (B), (C), 0, 0, 0)

__global__ __launch_bounds__(NT)
__attribute__((amdgpu_waves_per_eu(2, 2)))     // 2 waves/SIMD: 256-reg unified budget
void rnn2d_v7(
    const int*   __restrict__ x,
    const float* __restrict__ Wih,
    const float* __restrict__ Wiv,
    const float* __restrict__ bch,
    const float* __restrict__ Wout,
    const float* __restrict__ bout,
    const unsigned int* __restrict__ wchf,
    const unsigned int* __restrict__ wcvf,
    float*       __restrict__ out)
{
    __shared__ __attribute__((aligned(16))) bf16x8        wlds[8 * 10 * 64];   // 80 KB Wch LDS tier
    __shared__ __attribute__((aligned(16))) unsigned short stm[32 * 512];      // 32 KB states
    __shared__ __attribute__((aligned(16))) unsigned short Vb[32 * 512];       // 32 KB V (bf16)
    __shared__ __attribute__((aligned(16))) unsigned short hb[2][2][512];      // 4 KB h dbuf
    __shared__ __attribute__((aligned(16))) float          part[512 * 2];      // 4 KB pre-acts
    __shared__ int    xc[2][2][16];
    __shared__ float4 wred[2][8];

    const int tid = threadIdx.x;
    const int b0  = blockIdx.x * 2;
    const int w   = tid >> 6, l = tid & 63;
    const int r   = l & 15,  hi4 = l >> 4, rb = r & 1;
    const int w4  = w * 4;

    const float wih0 = Wih[tid], wih1 = Wih[512 + tid];
    const float wiv0 = Wiv[tid], wiv1 = Wiv[512 + tid];
    const float bc   = bch[tid];
    const float wo0  = Wout[2 * tid], wo1 = Wout[2 * tid + 1];
    const float bo0  = bout[0],       bo1 = bout[1];

    const bf16x8* __restrict__ WF = (const bf16x8*)wchf;
    const bf16x8* __restrict__ VF = (const bf16x8*)wcvf;

    for (int idx = tid; idx < 32 * 512 / 2; idx += NT) {
        ((unsigned*)stm)[idx] = 0;
        ((unsigned*)Vb)[idx]  = 0;
    }

    // ---- Wch residency map (per wave, 64 frags = 4 n-tiles x 16 kb) ----
    // AGPR: nt0 kb0-15 (wag0, 64 regs) + nt1 kb0-7 (wag1, 32 regs)
    // LDS : nt1 kb8-15 (q0-7) + nt2 kb0-1 (q8-9)
    // stream (30): nt2 kb2-15 + nt3 kb0-15, in 5 phases of 6
    bf16x8 wag0[16];
    #pragma unroll
    for (int kb = 0; kb < 16; ++kb)
        wag0[kb] = WF[(kb * 32 + w4 + 0) * 64 + l];
    bf16x8 wag1[8];
    #pragma unroll
    for (int kb = 0; kb < 8; ++kb)
        wag1[kb] = WF[(kb * 32 + w4 + 1) * 64 + l];
    #pragma unroll
    for (int q = 0; q < 8; ++q)
        wlds[(w * 10 + q) * 64 + l] = WF[((8 + q) * 32 + w4 + 1) * 64 + l];
    #pragma unroll
    for (int q = 0; q < 2; ++q)
        wlds[(w * 10 + 8 + q) * 64 + l] = WF[(q * 32 + w4 + 2) * 64 + l];

    bf16x8 SA[6], SB[6];
    #define LOAD_PH0(B_) { _Pragma("unroll") for (int j = 0; j < 6; ++j) \
        (B_)[j] = WF[((2 + j) * 32 + w4 + 2) * 64 + l]; }
    #define LOAD_PH1(B_) { _Pragma("unroll") for (int j = 0; j < 6; ++j) \
        (B_)[j] = WF[((8 + j) * 32 + w4 + 2) * 64 + l]; }
    #define LOAD_PH2(B_) { _Pragma("unroll") for (int j = 0; j < 2; ++j) \
        (B_)[j] = WF[((14 + j) * 32 + w4 + 2) * 64 + l]; \
        _Pragma("unroll") for (int j = 2; j < 6; ++j) \
        (B_)[j] = WF[((j - 2) * 32 + w4 + 3) * 64 + l]; }
    #define LOAD_PH3(B_) { _Pragma("unroll") for (int j = 0; j < 6; ++j) \
        (B_)[j] = WF[((4 + j) * 32 + w4 + 3) * 64 + l]; }
    #define LOAD_PH4(B_) { _Pragma("unroll") for (int j = 0; j < 6; ++j) \
        (B_)[j] = WF[((10 + j) * 32 + w4 + 3) * 64 + l]; }

    LOAD_PH0(SA);   // arm first step

    float logp0 = 0.f, logp1 = 0.f;
    int p = 0;

    for (int i = 0; i < 16; ++i) {
        const int dir = (i & 1) ? -1 : 1;

        // ---- per-row V-pass: Vb = st(prev row) @ Wcv, two n-halves ----
        if (i > 0) {
            const int kl = hi4 * 8;
            #pragma unroll
            for (int half = 0; half < 2; ++half) {
                f32x4 vacc[2][2];
                #pragma unroll
                for (int m = 0; m < 2; ++m)
                    #pragma unroll
                    for (int t4 = 0; t4 < 2; ++t4) vacc[m][t4] = (f32x4)(0.f);
                for (int kb = 0; kb < 16; ++kb) {
                    const int ka = kb * 32 + kl;
                    bf16x8 A0 = *(const bf16x8*)&stm[st_off(r,      ka)];
                    bf16x8 A1 = *(const bf16x8*)&stm[st_off(r + 16, ka)];
                    #pragma unroll
                    for (int t4 = 0; t4 < 2; ++t4) {
                        bf16x8 Bf = VF[(size_t)(kb * 32 + w4 + half * 2 + t4) * 64 + l];
                        vacc[0][t4] = IMFMA(A0, Bf, vacc[0][t4]);
                        vacc[1][t4] = IMFMA(A1, Bf, vacc[1][t4]);
                    }
                }
                #pragma unroll
                for (int m = 0; m < 2; ++m)
                    #pragma unroll
                    for (int t4 = 0; t4 < 2; ++t4)
                        #pragma unroll
                        for (int q = 0; q < 4; ++q)
                            Vb[(m * 16 + hi4 * 4 + q) * 512 +
                               (w4 + half * 2 + t4) * 16 + r] = f2bf(vacc[m][t4][q]);
            }
            LOAD_PH0(SA);   // re-arm (tail issue was skipped at t==15)
        }

        // x-row cache: [b][0]=row i, [b][1]=row i-1
        if (tid < 64) {
            const int b = tid >> 5, rs = (tid >> 4) & 1, c = tid & 15;
            int v = 0;
            if (rs == 0)      v = x[(b0 + b) * 256 + i * 16 + c];
            else if (i > 0)   v = x[(b0 + b) * 256 + (i - 1) * 16 + c];
            xc[b][rs][c] = v;
        }
        ((unsigned*)hb)[tid] = 0;    // zero hb[0] (p==0 at row start)
        __syncthreads();

        for (int t = 0; t < 16; ++t) {
            const int c = (dir == 1) ? t : 15 - t;

            f32x4 acc0 = (f32x4)(0.f), acc1 = (f32x4)(0.f),
                  acc2 = (f32x4)(0.f), acc3 = (f32x4)(0.f);

            #define AF(KB) (*(const bf16x8*)&hb[p][rb][(((KB) * 4 + hi4) ^ rb) << 3])

            LOAD_PH1(SB);
            // resident sweep 1: kb 0-7 (AGPR nt0, nt1; LDS nt2 kb0-1)
            #pragma unroll
            for (int kb = 0; kb < 8; ++kb) {
                bf16x8 af = AF(kb);
                mfma_a(acc0, af, wag0[kb]);
                mfma_a(acc1, af, wag1[kb]);
                if (kb < 2) mfma_v(acc2, af, wlds[(w * 10 + 8 + kb) * 64 + l]);
            }
            // consume ph0 (nt2 kb2-7 -> acc2)
            #pragma unroll
            for (int j = 0; j < 6; ++j) { bf16x8 af = AF(2 + j); mfma_v(acc2, af, SA[j]); }
            LOAD_PH2(SA);
            // resident sweep 2: kb 8-15 (AGPR nt0; LDS nt1)
            #pragma unroll
            for (int kb = 8; kb < 16; ++kb) {
                bf16x8 af = AF(kb);
                mfma_a(acc0, af, wag0[kb]);
                mfma_v(acc1, af, wlds[(w * 10 + kb - 8) * 64 + l]);
            }
            // consume ph1 (nt2 kb8-13 -> acc2)
            #pragma unroll
            for (int j = 0; j < 6; ++j) { bf16x8 af = AF(8 + j); mfma_v(acc2, af, SB[j]); }
            LOAD_PH3(SB);
            // consume ph2 (nt2 kb14-15 -> acc2; nt3 kb0-3 -> acc3)
            #pragma unroll
            for (int j = 0; j < 2; ++j) { bf16x8 af = AF(14 + j); mfma_v(acc2, af, SA[j]); }
            #pragma unroll
            for (int j = 2; j < 6; ++j) { bf16x8 af = AF(j - 2);  mfma_v(acc3, af, SA[j]); }
            LOAD_PH4(SA);
            // consume ph3 (nt3 kb4-9 -> acc3)
            #pragma unroll
            for (int j = 0; j < 6; ++j) { bf16x8 af = AF(4 + j); mfma_v(acc3, af, SB[j]); }
            // consume ph4 (nt3 kb10-15 -> acc3)
            #pragma unroll
            for (int j = 0; j < 6; ++j) { bf16x8 af = AF(10 + j); mfma_v(acc3, af, SA[j]); }
            // arm next step's ph0 (skip at t==15; re-armed after V-pass)
            if (t < 15) LOAD_PH0(SA);
            #undef AF

            // C rows 0,1 (= batches) live in lanes 0-15, regs 0,1
            if (l < 16) {
                *(float2*)&part[(w * 64 +  0 + l) * 2] = make_float2(acc0[0], acc0[1]);
                *(float2*)&part[(w * 64 + 16 + l) * 2] = make_float2(acc1[0], acc1[1]);
                *(float2*)&part[(w * 64 + 32 + l) * 2] = make_float2(acc2[0], acc2[1]);
                *(float2*)&part[(w * 64 + 48 + l) * 2] = make_float2(acc3[0], acc3[1]);
            }
            barL();   // [B]

            // ---- epilogue: u = tid, both batches (R4-R6 verified) ----
            const int  cl   = c - dir;
            const bool hasL = (t > 0);
            const bool hasV = (i > 0);
            const float2 pa = *(const float2*)&part[tid * 2];
            float v0 = pa.x + bf2f(Vb[(c * 2 + 0) * 512 + tid]) + bc;
            float v1 = pa.y + bf2f(Vb[(c * 2 + 1) * 512 + tid]) + bc;
            if (hasL) { v0 += xc[0][0][cl] ? wih1 : wih0;  v1 += xc[1][0][cl] ? wih1 : wih0; }
            if (hasV) { v0 += xc[0][1][c]  ? wiv1 : wiv0;  v1 += xc[1][1][c]  ? wiv1 : wiv0; }
            v0 = v0 > 0.f ? v0 : expm1f(v0);
            v1 = v1 > 0.f ? v1 : expm1f(v1);
            hb[p ^ 1][0][(((tid >> 3) ^ 0) << 3) | (tid & 7)] = f2bf(v0);
            hb[p ^ 1][1][(((tid >> 3) ^ 1) << 3) | (tid & 7)] = f2bf(v1);
            stm[st_off(c * 2 + 0, tid)] = f2bf(v0);
            stm[st_off(c * 2 + 1, tid)] = f2bf(v1);
            const int sc0 = xc[0][0][c], sc1 = xc[1][0][c];
            float lp0 = v0 * wo0, lp1 = v0 * wo1, lp2 = v1 * wo0, lp3 = v1 * wo1;
            #pragma unroll
            for (int off = 32; off; off >>= 1) {
                lp0 += __shfl_down(lp0, off);
                lp1 += __shfl_down(lp1, off);
                lp2 += __shfl_down(lp2, off);
                lp3 += __shfl_down(lp3, off);
            }
            if (l == 0) wred[t & 1][w] = make_float4(lp0, lp1, lp2, lp3);
            barL();   // [C]

            // ---- logits: all threads redundantly (no straggler wave) ----
            float g00 = bo0, g01 = bo1, g10 = bo0, g11 = bo1;
            #pragma unroll
            for (int ww = 0; ww < 8; ++ww) {
                const float4 v4 = wred[t & 1][ww];
                g00 += v4.x;  g01 += v4.y;  g10 += v4.z;  g11 += v4.w;
            }
            {
                const float m0 = fmaxf(g00, g01), m1 = fmaxf(g10, g11);
                const float ls0 = m0 + log1pf(expf(fminf(g00, g01) - m0));
                const float ls1 = m1 + log1pf(expf(fminf(g10, g11) - m1));
                logp0 += (sc0 ? g01 : g00) - ls0;
                logp1 += (sc1 ? g11 : g10) - ls1;
            }
            p ^= 1;
        }
    }

    if (tid < 2) {
        float v = tid ? logp1 : logp0;
        if (isnan(v)) v = 0.f;
        else if (isinf(v)) v = v > 0.f ? 3.4028235e38f : -3.4028235e38f;
        out[b0 + tid] = v;
    }
}

extern "C" void kernel_launch(void* const* d_in, const int* in_sizes, int n_in,
                              void* d_out, int out_size, void* d_ws, size_t ws_size,
                              hipStream_t stream) {
    const int*   x    = (const int*)  d_in[0];
    const float* Wih  = (const float*)d_in[1];
    const float* Wiv  = (const float*)d_in[2];
    const float* Wch  = (const float*)d_in[3];
    const float* bch  = (const float*)d_in[4];
    const float* Wcv  = (const float*)d_in[5];
    const float* Wout = (const float*)d_in[6];
    const float* bout = (const float*)d_in[7];

    unsigned int* ws_wch = (unsigned int*)d_ws;                          // 512 KB
    unsigned int* ws_wcv = (unsigned int*)((char*)d_ws + 512 * 1024);    // 512 KB

    conv_frag<<<1024, 64, 0, stream>>>(Wch, Wcv, ws_wch, ws_wcv);
    rnn2d_v7<<<NWG, NT, 0, stream>>>(x, Wih, Wiv, bch, Wout, bout,
                                     ws_wch, ws_wcv, (float*)d_out);
}